// Round 15
// baseline (62.225 us; speedup 1.0000x reference)
//
#include <hip/hip_runtime.h>

#define INV_T (1.0f / 0.07f)
#define EPSF 1e-8f

typedef float f32x4 __attribute__((ext_vector_type(4)));
typedef long longx2 __attribute__((ext_vector_type(2)));
typedef int i32x8 __attribute__((ext_vector_type(8)));

struct TrueT { static constexpr bool value = true; };
struct FalseT { static constexpr bool value = false; };

union frag_u { longx2 h[2]; i32x8 v; };

// 4 rows per block (one per wave): L2-normalize, cast to fp8 e4m3, zero num/den/acc2.
__global__ __launch_bounds__(256) void norm_kernel(const float* __restrict__ emb,
                                                   unsigned char* __restrict__ e8,
                                                   float* __restrict__ num,
                                                   float* __restrict__ den,
                                                   float* __restrict__ acc2,
                                                   int D) {
  const int wave = threadIdx.x >> 6;
  const int lane = threadIdx.x & 63;
  const int row = blockIdx.x * 4 + wave;
  const float4* src = (const float4*)(emb + (size_t)row * D);
  float4 v0 = src[lane];
  float4 v1 = src[lane + 64];
  float ss = v0.x * v0.x + v0.y * v0.y + v0.z * v0.z + v0.w * v0.w +
             v1.x * v1.x + v1.y * v1.y + v1.z * v1.z + v1.w * v1.w;
#pragma unroll
  for (int m = 32; m >= 1; m >>= 1) ss += __shfl_xor(ss, m, 64);
  const float r = 1.0f / sqrtf(ss);
  int w0 = __builtin_amdgcn_cvt_pk_fp8_f32(v0.x * r, v0.y * r, 0, false);
  w0 = __builtin_amdgcn_cvt_pk_fp8_f32(v0.z * r, v0.w * r, w0, true);
  int w1 = __builtin_amdgcn_cvt_pk_fp8_f32(v1.x * r, v1.y * r, 0, false);
  w1 = __builtin_amdgcn_cvt_pk_fp8_f32(v1.z * r, v1.w * r, w1, true);
  unsigned int* dst = (unsigned int*)(e8 + (size_t)row * D);
  dst[lane] = (unsigned int)w0;
  dst[64 + lane] = (unsigned int)w1;
  if (lane == 0) { num[row] = 0.f; den[row] = 0.f; }
  if (blockIdx.x == 0 && threadIdx.x < 2) acc2[threadIdx.x] = 0.f;
}

// Upper-block-triangle of sim = e.e^T. 128x128 tile, 4 waves (2x2), (256,3)
// -> 3 blocks/CU. MX-scaled fp8 K=128 (unit scales 0x7F = 1.0): one MFMA per
// (m,n) per 128-k super-tile -> MFMA pipe time halves vs non-scaled fp8
// (4661 vs 2047 TF) and instruction count drops 4x. C/D layout is
// shape-determined -> epilogue identical to r12-r14 (verified absmax 0.0).
// LDS: single 32KB buffer [A 16KB | B 16KB], rows 128B, swizzle
// col ^ ((row&7)<<4) (fragment rows = base+16m -> XOR is per-thread constant;
// reads AND writes at the uniform 8-words/bank ds_*_b128 floor).
// Staging: T14 depth-1 reg prefetch -- loads(st+1) issue under compute(st),
// ds_writes after the readers' barrier.
template <int D, int KT>   // KT = D/128 super-tiles
__global__ __launch_bounds__(256, 3) void sim_kernel(
    const unsigned char* __restrict__ E,    // fp8 normalized, N x D
    const int* __restrict__ labels,         // int32 (harness converts int64)
    float* __restrict__ num, float* __restrict__ den) {
  __shared__ __align__(16) char smem[40960];   // 32KB stage | 40KB epilogue arena
  float* red = (float*)smem;

  const int tid = threadIdx.x;
  const int lane = tid & 63;
  const int wave = tid >> 6;               // 0..3
  const int wm = wave >> 1, wn = wave & 1; // 2x2 wave grid: 64x64 per wave
  const int fr = lane & 15;
  const int fk = lane >> 4;

  // XCD chunking (2080 = 8*260), then triangular decode t = bb*(bb+1)/2 + ba
  const int bid = blockIdx.x;
  const int t = (bid & 7) * 260 + (bid >> 3);
  int bb = (int)((sqrtf(8.0f * (float)t + 1.0f) - 1.0f) * 0.5f);
  while ((bb + 1) * (bb + 2) / 2 <= t) ++bb;
  while (bb * (bb + 1) / 2 > t) --bb;
  const int ba = t - bb * (bb + 1) / 2;
  const int i0 = ba * 128;
  const int j0 = bb * 128;
  const bool diag = (i0 == j0);

  f32x4 acc[4][4] = {};

  // fragment ds_read addressing: row = (wm|wn)*64 + m*16 + fr -> row&7 = fr&7
  // (per-thread const). addr = row*128 + m*2048 + ((fk*32 + u2*16) ^ sw)
  const int sw = (fr & 7) << 4;
  const int c0 = (fk * 32) ^ sw;
  const int c1 = (fk * 32 + 16) ^ sw;
  const int abase = (wm * 64 + fr) * 128;            // + m*2048 + c0/c1
  const int bbase = 16384 + (wn * 64 + fr) * 128;    // + n*2048 + c0/c1

  // staging: thread handles row = tid>>1, 64B half = (tid&1)*64 of each matrix
  const int srow = tid >> 1;
  const int shalf = (tid & 1) * 64;
  const unsigned char* gA = E + (size_t)(i0 + srow) * D + shalf;
  const unsigned char* gB = E + (size_t)(j0 + srow) * D + shalf;
  const int ssw = (srow & 7) << 4;
  const int wbase = srow * 128;                       // + ((shalf + u*16) ^ ssw)

  longx2 P[8];   // 128 B in-flight: 4x16B per matrix

  auto loadR = [&](int st) {
    const int kb = st * 128;
#pragma unroll
    for (int u = 0; u < 4; ++u) {
      P[u] = *(const longx2*)(gA + kb + u * 16);
      P[4 + u] = *(const longx2*)(gB + kb + u * 16);
    }
  };

  auto dsW = [&]() {
#pragma unroll
    for (int u = 0; u < 4; ++u) {
      *(longx2*)(smem + wbase + ((shalf + u * 16) ^ ssw)) = P[u];
      *(longx2*)(smem + 16384 + wbase + ((shalf + u * 16) ^ ssw)) = P[4 + u];
    }
  };

  auto compute = [&]() {
    frag_u A[4], B[4];
#pragma unroll
    for (int m = 0; m < 4; ++m) {
      A[m].h[0] = *(const longx2*)(smem + abase + m * 2048 + c0);
      A[m].h[1] = *(const longx2*)(smem + abase + m * 2048 + c1);
    }
#pragma unroll
    for (int n = 0; n < 4; ++n) {
      B[n].h[0] = *(const longx2*)(smem + bbase + n * 2048 + c0);
      B[n].h[1] = *(const longx2*)(smem + bbase + n * 2048 + c1);
    }
    __builtin_amdgcn_s_setprio(1);
#pragma unroll
    for (int m = 0; m < 4; ++m)
#pragma unroll
      for (int n = 0; n < 4; ++n)
        acc[m][n] = __builtin_amdgcn_mfma_scale_f32_16x16x128_f8f6f4(
            A[m].v, B[n].v, acc[m][n], 0, 0,
            0, 0x7F7F7F7F, 0, 0x7F7F7F7F);   // unit E8M0 scales
    __builtin_amdgcn_s_setprio(0);
  };

#define BARRIER_SEQ                                           \
  asm volatile("s_waitcnt lgkmcnt(0)" ::: "memory");          \
  __builtin_amdgcn_sched_barrier(0);                          \
  __builtin_amdgcn_s_barrier();                               \
  __builtin_amdgcn_sched_barrier(0);

  // prologue: super-tile 0 -> LDS
  loadR(0);
  dsW();               // compiler inserts counted vmcnt for the reg deps
  BARRIER_SEQ;

#pragma unroll
  for (int st = 0; st < KT; ++st) {
    if (st + 1 < KT) loadR(st + 1);       // T14: issue under compute
    compute();
    if (st + 1 < KT) {
      __builtin_amdgcn_s_barrier();       // all readers of buffer done
      __builtin_amdgcn_sched_barrier(0);
      dsW();
      BARRIER_SEQ;                        // writes visible
    }
  }
  __syncthreads();     // drain; smem reusable for epilogue

  // ---- epilogue (r12/r13/r14-verified, bit-identical) ----
  // acc[m][n][r]: i = i0 + wm*64 + m*16 + fk*4 + r ; j = j0 + wn*64 + n*16 + fr
  int jcol[4], labj[4];
#pragma unroll
  for (int n = 0; n < 4; ++n) {
    jcol[n] = j0 + wn * 64 + n * 16 + fr;
    labj[n] = labels[jcol[n]];
  }
  float cd[4] = {0.f, 0.f, 0.f, 0.f}, cn[4] = {0.f, 0.f, 0.f, 0.f};

  auto epilogue = [&](auto DIAG) {
#pragma unroll
    for (int m = 0; m < 4; ++m) {
      float pdm[4] = {0.f, 0.f, 0.f, 0.f}, pnm[4] = {0.f, 0.f, 0.f, 0.f};
      const int ibase = i0 + wm * 64 + m * 16 + fk * 4;
      int li[4];
#pragma unroll
      for (int r = 0; r < 4; ++r) li[r] = labels[ibase + r];
#pragma unroll
      for (int n = 0; n < 4; ++n) {
#pragma unroll
        for (int r = 0; r < 4; ++r) {
          const float s = acc[m][n][r] * INV_T;
          const float es = __expf(s);
          if (DIAG.value) {
            if (jcol[n] != ibase + r) {
              pdm[r] += es;
              if (li[r] == labj[n] && s > 0.0f) pnm[r] += es;
            }
          } else {
            pdm[r] += es;
            cd[n] += es;
            if (li[r] == labj[n] && s > 0.0f) { pnm[r] += es; cn[n] += es; }
          }
        }
      }
      // scatter: word = ((wave*4+m)*64 + (lane ^ (m<<2)))*5 + r
      const int base = ((wave * 4 + m) * 64 + (lane ^ (m << 2))) * 5;
#pragma unroll
      for (int r = 0; r < 4; ++r) {
        red[base + r] = pdm[r];
        red[5120 + base + r] = pnm[r];
      }
    }
  };

  if (diag) epilogue(TrueT{}); else epilogue(FalseT{});

  if (!diag) {
    // col partials: j depends on (n, fr) only; reduce over fk (lanes xor 16,32)
#pragma unroll
    for (int sh = 16; sh < 64; sh <<= 1) {
#pragma unroll
      for (int n = 0; n < 4; ++n) {
        cd[n] += __shfl_xor(cd[n], sh, 64);
        cn[n] += __shfl_xor(cn[n], sh, 64);
      }
    }
    if (fk == 0) {
#pragma unroll
      for (int n = 0; n < 4; ++n) {
        atomicAdd(&den[jcol[n]], cd[n]);
        atomicAdd(&num[jcol[n]], cn[n]);
      }
    }
  }

  __syncthreads();
  // consumer: tid<128 -> den rows, tid>=128 -> num rows; 32 summands each
  {
    const int which = tid >> 7;                  // 0: pd->den, 1: pn->num
    const int ri = tid & 127;                    // local row
    const int cwm = ri >> 6, cm = (ri >> 4) & 3, cfk = (ri >> 2) & 3, cr = ri & 3;
    const float* src = red + which * 5120;
    float v = 0.f;
#pragma unroll
    for (int w2 = 0; w2 < 2; ++w2)
#pragma unroll
      for (int f2 = 0; f2 < 16; ++f2)
        v += src[(((cwm * 2 + w2) * 4 + cm) * 64 + ((cfk * 16 + f2) ^ (cm << 2))) * 5 + cr];
    atomicAdd((which ? num : den) + i0 + ri, v);
  }
}

// 16 blocks: per-row loss, block-reduce, atomicAdd into acc2[0]=sum, [1]=count.
__global__ __launch_bounds__(256) void loss_reduce(const float* __restrict__ num,
                                                   const float* __restrict__ den,
                                                   float* __restrict__ acc2, int N) {
  const int tid = threadIdx.x;
  int i = blockIdx.x * 512 + tid;
  float sum = 0.f, cnt = 0.f;
#pragma unroll
  for (int k = 0; k < 2; ++k, i += 256) {
    const float n = num[i], d = den[i];
    if (n > 0.f && d > 0.f) {
      sum += logf(d + EPSF) - logf(n);
      cnt += 1.f;
    }
  }
#pragma unroll
  for (int m = 32; m >= 1; m >>= 1) {
    sum += __shfl_xor(sum, m, 64);
    cnt += __shfl_xor(cnt, m, 64);
  }
  __shared__ float s1[4], s2[4];
  if ((tid & 63) == 0) { s1[tid >> 6] = sum; s2[tid >> 6] = cnt; }
  __syncthreads();
  if (tid == 0) {
    atomicAdd(&acc2[0], s1[0] + s1[1] + s1[2] + s1[3]);
    atomicAdd(&acc2[1], s2[0] + s2[1] + s2[2] + s2[3]);
  }
}

__global__ void final_kernel(const float* __restrict__ acc2, float* __restrict__ out) {
  const float S = acc2[0], C = acc2[1];
  out[0] = (C > 0.f) ? fabsf(S / C) : 0.f;
}

extern "C" void kernel_launch(void* const* d_in, const int* in_sizes, int n_in,
                              void* d_out, int out_size, void* d_ws, size_t ws_size,
                              hipStream_t stream) {
  const float* emb = (const float*)d_in[0];
  const int* labels = (const int*)d_in[1];
  float* out = (float*)d_out;

  const int N = in_sizes[1];          // 8192
  const int D = in_sizes[0] / N;      // 512

  unsigned char* e8 = (unsigned char*)d_ws;                    // N*D fp8 = 4 MB
  float* num = (float*)((char*)d_ws + (size_t)N * D);          // N f32
  float* den = num + N;                                        // N f32
  float* acc2 = den + N;                                       // 2 f32

  norm_kernel<<<N / 4, 256, 0, stream>>>(emb, e8, num, den, acc2, D);
  const int nb = N / 128;                       // 64
  const int tri = nb * (nb + 1) / 2;            // 2080
  sim_kernel<512, 4><<<tri, 256, 0, stream>>>(e8, labels, num, den);
  loss_reduce<<<N / 512, 256, 0, stream>>>(num, den, acc2, N);
  final_kernel<<<1, 1, 0, stream>>>(acc2, out);
}

// Round 16
// 55.489 us; speedup vs baseline: 1.1214x; 1.1214x over previous
//
#include <hip/hip_runtime.h>

#define INV_T (1.0f / 0.07f)
#define EPSF 1e-8f

typedef float f32x4 __attribute__((ext_vector_type(4)));
typedef long longx2 __attribute__((ext_vector_type(2)));

struct TrueT { static constexpr bool value = true; };
struct FalseT { static constexpr bool value = false; };

// 4 rows per block (one per wave): L2-normalize, cast to fp8 e4m3, zero num/den/acc2.
__global__ __launch_bounds__(256) void norm_kernel(const float* __restrict__ emb,
                                                   unsigned char* __restrict__ e8,
                                                   float* __restrict__ num,
                                                   float* __restrict__ den,
                                                   float* __restrict__ acc2,
                                                   int D) {
  const int wave = threadIdx.x >> 6;
  const int lane = threadIdx.x & 63;
  const int row = blockIdx.x * 4 + wave;
  const float4* src = (const float4*)(emb + (size_t)row * D);
  float4 v0 = src[lane];
  float4 v1 = src[lane + 64];
  float ss = v0.x * v0.x + v0.y * v0.y + v0.z * v0.z + v0.w * v0.w +
             v1.x * v1.x + v1.y * v1.y + v1.z * v1.z + v1.w * v1.w;
#pragma unroll
  for (int m = 32; m >= 1; m >>= 1) ss += __shfl_xor(ss, m, 64);
  const float r = 1.0f / sqrtf(ss);
  int w0 = __builtin_amdgcn_cvt_pk_fp8_f32(v0.x * r, v0.y * r, 0, false);
  w0 = __builtin_amdgcn_cvt_pk_fp8_f32(v0.z * r, v0.w * r, w0, true);
  int w1 = __builtin_amdgcn_cvt_pk_fp8_f32(v1.x * r, v1.y * r, 0, false);
  w1 = __builtin_amdgcn_cvt_pk_fp8_f32(v1.z * r, v1.w * r, w1, true);
  unsigned int* dst = (unsigned int*)(e8 + (size_t)row * D);
  dst[lane] = (unsigned int)w0;
  dst[64 + lane] = (unsigned int)w1;
  if (lane == 0) { num[row] = 0.f; den[row] = 0.f; }
  if (blockIdx.x == 0 && threadIdx.x < 2) acc2[threadIdx.x] = 0.f;
}

// Upper-block-triangle of sim = e.e^T. 128x128 tile, 4 waves (2x2), (256,3)
// -> 3 blocks/CU. FP8 kk-PAIR LDS LAYOUT (r14-verified, best measured):
// per row (64B super-tile, BK=64), 16B unit u holds
// [kk0: G[k+u*8..+7] | kk1: G[k+32+u*8..+7]] -- one ds_read_b128 per fragment
// serves TWO MFMA k-steps, start banks span all 32 banks -> conflict-free.
// Reg staging (T14, depth-2): loads(t+2) issued before compute(t),
// ds_writes(t+1) after; compiler counted-vmcnt; 1 lgkm+barrier per super-tile.
template <int D, int KT>   // KT = D/64 super-tiles
__global__ __launch_bounds__(256, 3) void sim_kernel(
    const unsigned char* __restrict__ E,    // fp8 normalized, N x D
    const int* __restrict__ labels,         // int32 (harness converts int64)
    float* __restrict__ num, float* __restrict__ den) {
  __shared__ __align__(16) char smem[40960];   // 2 x 16KB stage bufs | 40KB epilogue
  float* red = (float*)smem;

  const int tid = threadIdx.x;
  const int lane = tid & 63;
  const int wave = tid >> 6;               // 0..3
  const int wm = wave >> 1, wn = wave & 1; // 2x2 wave grid: 64x64 per wave
  const int fr = lane & 15;
  const int fk = lane >> 4;

  // XCD chunking (2080 = 8*260), then triangular decode t = bb*(bb+1)/2 + ba
  const int bid = blockIdx.x;
  const int t = (bid & 7) * 260 + (bid >> 3);
  int bb = (int)((sqrtf(8.0f * (float)t + 1.0f) - 1.0f) * 0.5f);
  while ((bb + 1) * (bb + 2) / 2 <= t) ++bb;
  while (bb * (bb + 1) / 2 > t) --bb;
  const int ba = t - bb * (bb + 1) / 2;
  const int i0 = ba * 128;
  const int j0 = bb * 128;
  const bool diag = (i0 == j0);

  f32x4 acc[4][4] = {};

  // frag read offsets: (row)*64 + fk*16, frag m at +m*1024 (16 rows)
  const int aoff0 = (wm * 64 + fr) * 64 + fk * 16;
  const int boff0 = (wn * 64 + fr) * 64 + fk * 16;

  // staging thread map: row = tid>>2 (plus h*64), u = tid&3
  const unsigned char* gA = E + (size_t)(i0 + (tid >> 2)) * D + (tid & 3) * 8;
  const unsigned char* gB = E + (size_t)(j0 + (tid >> 2)) * D + (tid & 3) * 8;
  const int woff = (tid >> 2) * 64 + (tid & 3) * 16;

  long Pa[8], Pb[8];

  auto loadR = [&](int st, long (&P)[8]) {
    const int kb = st * 64;
    P[0] = *(const long*)(gA + kb);
    P[1] = *(const long*)(gA + kb + 32);
    P[2] = *(const long*)(gA + (size_t)64 * D + kb);
    P[3] = *(const long*)(gA + (size_t)64 * D + kb + 32);
    P[4] = *(const long*)(gB + kb);
    P[5] = *(const long*)(gB + kb + 32);
    P[6] = *(const long*)(gB + (size_t)64 * D + kb);
    P[7] = *(const long*)(gB + (size_t)64 * D + kb + 32);
  };

  auto dsW = [&](int buf, const long (&P)[8]) {
    char* base = smem + buf * 16384;
    *(longx2*)(base + woff) = longx2{P[0], P[1]};
    *(longx2*)(base + woff + 4096) = longx2{P[2], P[3]};
    *(longx2*)(base + 8192 + woff) = longx2{P[4], P[5]};
    *(longx2*)(base + 8192 + woff + 4096) = longx2{P[6], P[7]};
  };

  auto compute = [&](int buf) {
    const char* Ab = smem + buf * 16384 + aoff0;
    const char* Bb = smem + buf * 16384 + 8192 + boff0;
    longx2 A[4], B[4];
#pragma unroll
    for (int m = 0; m < 4; ++m) A[m] = *(const longx2*)(Ab + m * 1024);
#pragma unroll
    for (int n = 0; n < 4; ++n) B[n] = *(const longx2*)(Bb + n * 1024);
    __builtin_amdgcn_s_setprio(1);
#pragma unroll
    for (int kk = 0; kk < 2; ++kk)
#pragma unroll
      for (int m = 0; m < 4; ++m)
#pragma unroll
        for (int n = 0; n < 4; ++n)
          acc[m][n] = __builtin_amdgcn_mfma_f32_16x16x32_fp8_fp8(A[m][kk], B[n][kk], acc[m][n], 0, 0, 0);
    __builtin_amdgcn_s_setprio(0);
  };

#define BARRIER_SEQ                                           \
  asm volatile("s_waitcnt lgkmcnt(0)" ::: "memory");          \
  __builtin_amdgcn_sched_barrier(0);                          \
  __builtin_amdgcn_s_barrier();                               \
  __builtin_amdgcn_sched_barrier(0);

  // prologue: super-tile 0 staged to buf0; tile 1 loaded to regs
  loadR(0, Pa);
  dsW(0, Pa);            // compiler inserts counted vmcnt before writes
  loadR(1, Pb);
  BARRIER_SEQ;

#pragma unroll
  for (int st = 0; st < KT; ++st) {
    if (st & 1) {
      if (st + 2 < KT) loadR(st + 2, Pb);
      compute(1);
      if (st + 1 < KT) { dsW(0, Pa); BARRIER_SEQ; }
    } else {
      if (st + 2 < KT) loadR(st + 2, Pa);
      compute(0);
      if (st + 1 < KT) { dsW(1, Pb); BARRIER_SEQ; }
    }
  }
  __syncthreads();       // full drain; smem reusable for epilogue

  // ---- epilogue (r12/r13/r14-verified) ----
  // acc[m][n][r]: i = i0 + wm*64 + m*16 + fk*4 + r ; j = j0 + wn*64 + n*16 + fr
  int jcol[4], labj[4];
#pragma unroll
  for (int n = 0; n < 4; ++n) {
    jcol[n] = j0 + wn * 64 + n * 16 + fr;
    labj[n] = labels[jcol[n]];
  }
  float cd[4] = {0.f, 0.f, 0.f, 0.f}, cn[4] = {0.f, 0.f, 0.f, 0.f};

  auto epilogue = [&](auto DIAG) {
#pragma unroll
    for (int m = 0; m < 4; ++m) {
      float pdm[4] = {0.f, 0.f, 0.f, 0.f}, pnm[4] = {0.f, 0.f, 0.f, 0.f};
      const int ibase = i0 + wm * 64 + m * 16 + fk * 4;
      int li[4];
#pragma unroll
      for (int r = 0; r < 4; ++r) li[r] = labels[ibase + r];
#pragma unroll
      for (int n = 0; n < 4; ++n) {
#pragma unroll
        for (int r = 0; r < 4; ++r) {
          const float s = acc[m][n][r] * INV_T;
          const float es = __expf(s);
          if (DIAG.value) {
            if (jcol[n] != ibase + r) {
              pdm[r] += es;
              if (li[r] == labj[n] && s > 0.0f) pnm[r] += es;
            }
          } else {
            pdm[r] += es;
            cd[n] += es;
            if (li[r] == labj[n] && s > 0.0f) { pnm[r] += es; cn[n] += es; }
          }
        }
      }
      // scatter: word = ((wave*4+m)*64 + (lane ^ (m<<2)))*5 + r
      const int base = ((wave * 4 + m) * 64 + (lane ^ (m << 2))) * 5;
#pragma unroll
      for (int r = 0; r < 4; ++r) {
        red[base + r] = pdm[r];
        red[5120 + base + r] = pnm[r];
      }
    }
  };

  if (diag) epilogue(TrueT{}); else epilogue(FalseT{});

  if (!diag) {
    // col partials: j depends on (n, fr) only; reduce over fk (lanes xor 16,32)
#pragma unroll
    for (int sh = 16; sh < 64; sh <<= 1) {
#pragma unroll
      for (int n = 0; n < 4; ++n) {
        cd[n] += __shfl_xor(cd[n], sh, 64);
        cn[n] += __shfl_xor(cn[n], sh, 64);
      }
    }
    if (fk == 0) {
#pragma unroll
      for (int n = 0; n < 4; ++n) {
        atomicAdd(&den[jcol[n]], cd[n]);
        atomicAdd(&num[jcol[n]], cn[n]);
      }
    }
  }

  __syncthreads();
  // consumer: tid<128 -> den rows, tid>=128 -> num rows; 32 summands each
  {
    const int which = tid >> 7;                  // 0: pd->den, 1: pn->num
    const int ri = tid & 127;                    // local row
    const int cwm = ri >> 6, cm = (ri >> 4) & 3, cfk = (ri >> 2) & 3, cr = ri & 3;
    const float* src = red + which * 5120;
    float v = 0.f;
#pragma unroll
    for (int w2 = 0; w2 < 2; ++w2)
#pragma unroll
      for (int f2 = 0; f2 < 16; ++f2)
        v += src[(((cwm * 2 + w2) * 4 + cm) * 64 + ((cfk * 16 + f2) ^ (cm << 2))) * 5 + cr];
    atomicAdd((which ? num : den) + i0 + ri, v);
  }
}

// 16 blocks: per-row loss, block-reduce, atomicAdd into acc2[0]=sum, [1]=count.
__global__ __launch_bounds__(256) void loss_reduce(const float* __restrict__ num,
                                                   const float* __restrict__ den,
                                                   float* __restrict__ acc2, int N) {
  const int tid = threadIdx.x;
  int i = blockIdx.x * 512 + tid;
  float sum = 0.f, cnt = 0.f;
#pragma unroll
  for (int k = 0; k < 2; ++k, i += 256) {
    const float n = num[i], d = den[i];
    if (n > 0.f && d > 0.f) {
      sum += logf(d + EPSF) - logf(n);
      cnt += 1.f;
    }
  }
#pragma unroll
  for (int m = 32; m >= 1; m >>= 1) {
    sum += __shfl_xor(sum, m, 64);
    cnt += __shfl_xor(cnt, m, 64);
  }
  __shared__ float s1[4], s2[4];
  if ((tid & 63) == 0) { s1[tid >> 6] = sum; s2[tid >> 6] = cnt; }
  __syncthreads();
  if (tid == 0) {
    atomicAdd(&acc2[0], s1[0] + s1[1] + s1[2] + s1[3]);
    atomicAdd(&acc2[1], s2[0] + s2[1] + s2[2] + s2[3]);
  }
}

__global__ void final_kernel(const float* __restrict__ acc2, float* __restrict__ out) {
  const float S = acc2[0], C = acc2[1];
  out[0] = (C > 0.f) ? fabsf(S / C) : 0.f;
}

extern "C" void kernel_launch(void* const* d_in, const int* in_sizes, int n_in,
                              void* d_out, int out_size, void* d_ws, size_t ws_size,
                              hipStream_t stream) {
  const float* emb = (const float*)d_in[0];
  const int* labels = (const int*)d_in[1];
  float* out = (float*)d_out;

  const int N = in_sizes[1];          // 8192
  const int D = in_sizes[0] / N;      // 512

  unsigned char* e8 = (unsigned char*)d_ws;                    // N*D fp8 = 4 MB
  float* num = (float*)((char*)d_ws + (size_t)N * D);          // N f32
  float* den = num + N;                                        // N f32
  float* acc2 = den + N;                                       // 2 f32

  norm_kernel<<<N / 4, 256, 0, stream>>>(emb, e8, num, den, acc2, D);
  const int nb = N / 128;                       // 64
  const int tri = nb * (nb + 1) / 2;            // 2080
  sim_kernel<512, 8><<<tri, 256, 0, stream>>>(e8, labels, num, den);
  loss_reduce<<<N / 512, 256, 0, stream>>>(num, den, acc2, N);
  final_kernel<<<1, 1, 0, stream>>>(acc2, out);
}